// Round 1
// baseline (111.975 us; speedup 1.0000x reference)
//
#include <hip/hip_runtime.h>

#define NBDT_BATCH 16384
#define NBDT_C 1024

// sigmoid(x) = 1/(1+exp(-x)); v_exp + v_rcp, ~1 ulp each.
__device__ __forceinline__ float fast_sigmoid(float x) {
    return __builtin_amdgcn_rcpf(1.0f + __expf(-x));
}

// One wave per row. Lane i owns leaves [8i, 8i+8) of EACH 512-leaf half
// (k=0 -> +0, k=1 -> +512). Loads/stores are 16B/lane at 32B stride: lane
// pairs (2j,2j+1) cover each 64B line half-and-half across the two float4
// accesses, so lines are fully consumed and HBM traffic is exactly 1x.
//
// Tree decomposition per half k:
//   blk 1,2,4 : in-lane within the 8-leaf chunk (7 nodes, down-sweep)
//   blk 8..256: butterfly shfl_xor stages on the chunk sum s8 (6 diffs)
//   blk 512   : root, lane-uniform (s512[0] vs s512[1])
// The 7 ancestor sigmoids of a lane's chunk are folded into a single
// P = rcp( prod_{i}(1 + exp(-d_i/blk_i)) )  -- 7 exps + 1 rcp instead of
// 7 exp + 7 rcp + 6 mul.
__global__ __launch_bounds__(256) void nbdt_kernel(const float* __restrict__ x,
                                                   float* __restrict__ y) {
    const int wave = (blockIdx.x * 256 + threadIdx.x) >> 6;
    const int lane = threadIdx.x & 63;
    const size_t rowbase = (size_t)wave * NBDT_C + (size_t)lane * 8;
    const float* xp = x + rowbase;
    float* yp = y + rowbase;

    float4 v[2][2];
#pragma unroll
    for (int k = 0; k < 2; ++k) {
        v[k][0] = *reinterpret_cast<const float4*>(xp + k * 512);
        v[k][1] = *reinterpret_cast<const float4*>(xp + k * 512 + 4);
    }

    // up-sweep: in-lane sums, then 6-stage butterfly per half
    float s4[2][2], d[2][6], s512[2];
#pragma unroll
    for (int k = 0; k < 2; ++k) {
        s4[k][0] = (v[k][0].x + v[k][0].y) + (v[k][0].z + v[k][0].w);
        s4[k][1] = (v[k][1].x + v[k][1].y) + (v[k][1].z + v[k][1].w);
        float acc = s4[k][0] + s4[k][1];  // s8: lane's chunk sum
        float t;
        t = __shfl_xor(acc, 1);  d[k][0] = acc - t; acc += t;  // children blk=8
        t = __shfl_xor(acc, 2);  d[k][1] = acc - t; acc += t;  // blk=16
        t = __shfl_xor(acc, 4);  d[k][2] = acc - t; acc += t;  // blk=32
        t = __shfl_xor(acc, 8);  d[k][3] = acc - t; acc += t;  // blk=64
        t = __shfl_xor(acc, 16); d[k][4] = acc - t; acc += t;  // blk=128
        t = __shfl_xor(acc, 32); d[k][5] = acc - t; acc += t;  // blk=256
        s512[k] = acc;                                         // lane-uniform
    }

    // root (children blk=512): need both orientations for the two halves
    const float xr = (s512[0] - s512[1]) * (1.0f / 512.0f);
    const float eR[2] = { __expf(-xr), __expf(xr) };

#pragma unroll
    for (int k = 0; k < 2; ++k) {
        // P(lane's 8-leaf chunk) = product of the 7 ancestor child-probs
        float q = 1.0f + eR[k];
        q *= 1.0f + __expf(d[k][5] * (-1.0f / 256.0f));
        q *= 1.0f + __expf(d[k][4] * (-1.0f / 128.0f));
        q *= 1.0f + __expf(d[k][3] * (-1.0f / 64.0f));
        q *= 1.0f + __expf(d[k][2] * (-1.0f / 32.0f));
        q *= 1.0f + __expf(d[k][1] * (-1.0f / 16.0f));
        q *= 1.0f + __expf(d[k][0] * (-1.0f / 8.0f));
        const float P = __builtin_amdgcn_rcpf(q);

        // down-sweep: blk=4, then blk=2, blk=1; complements are exact
        float c0 = P * fast_sigmoid((s4[k][0] - s4[k][1]) * 0.25f);
        float c1 = P - c0;

        float4 a = v[k][0];
        float4 b = v[k][1];
        float4 o0, o1;

        float e0 = c0 * fast_sigmoid(((a.x + a.y) - (a.z + a.w)) * 0.5f);
        float e1 = c0 - e0;
        o0.x = e0 * fast_sigmoid(a.x - a.y);  o0.y = e0 - o0.x;
        o0.z = e1 * fast_sigmoid(a.z - a.w);  o0.w = e1 - o0.z;

        float f0 = c1 * fast_sigmoid(((b.x + b.y) - (b.z + b.w)) * 0.5f);
        float f1 = c1 - f0;
        o1.x = f0 * fast_sigmoid(b.x - b.y);  o1.y = f0 - o1.x;
        o1.z = f1 * fast_sigmoid(b.z - b.w);  o1.w = f1 - o1.z;

        *reinterpret_cast<float4*>(yp + k * 512)     = o0;
        *reinterpret_cast<float4*>(yp + k * 512 + 4) = o1;
    }
}

extern "C" void kernel_launch(void* const* d_in, const int* in_sizes, int n_in,
                              void* d_out, int out_size, void* d_ws, size_t ws_size,
                              hipStream_t stream) {
    const float* x = (const float*)d_in[0];
    float* y = (float*)d_out;
    // 16384 rows, 1 row per wave, 4 waves per 256-thread block -> 4096 blocks.
    dim3 grid(NBDT_BATCH / 4);
    dim3 block(256);
    nbdt_kernel<<<grid, block, 0, stream>>>(x, y);
}